// Round 15
// baseline (837.119 us; speedup 1.0000x reference)
//
#include <hip/hip_runtime.h>

// ============================================================================
// Bidirectional LSTM encoder, MI355X.  R15: R14 + early poll issue + fat prep.
//   - polls for step s+1 issued right after publish(s): retry rounds overlap
//     the xW compute instead of idling (verify window still polls-only).
//   - aemb gather: 512 blocks x 16 rows (was 8192 tiny blocks).
//   - everything else R12/R14-validated: 4 domains, tag-in-data, quad-packed
//     publish, 1 RAWBAR/step, in-wave quad transpose gates, xW fold.
// ============================================================================

typedef unsigned short u16;
typedef unsigned int   u32;
typedef u16   u16x8 __attribute__((ext_vector_type(8)));
typedef u32   u32x4 __attribute__((ext_vector_type(4)));
typedef __bf16 bf16x8 __attribute__((ext_vector_type(8)));
typedef float f32x4 __attribute__((ext_vector_type(4)));

#define EP 320            // padded E (300 -> 320)
#define EPL 328           // LDS row stride (pad -> 2-way banks only)

static const size_t OFF_AEMB = 0;                              // 8192*320*2
static const size_t OFF_WPT  = OFF_AEMB + (size_t)8192*EP*2;
static const size_t OFF_BIAS = OFF_WPT  + (size_t)4096*EP*2;   // f32[4096]
static const size_t OFF_UPT  = OFF_BIAS + (size_t)4096*4;      // bf16 [4096][512]
static const size_t OFF_MASK = OFF_UPT  + (size_t)4096*512*2;  // u32 [32][8]
static const size_t OFF_HIMG = OFF_MASK + 1024;                // u32 4dom*2par*8192 dwords

__device__ __forceinline__ u16 f2bf(float f){               // RNE
  u32 u = __builtin_bit_cast(u32, f);
  return (u16)((u + 0x7FFFu + ((u >> 16) & 1u)) >> 16);
}
__device__ __forceinline__ float sigm(float x){ return 1.f/(1.f+__expf(-x)); }
__device__ __forceinline__ float tanh_(float x){ return 2.f/(1.f+__expf(-2.f*x)) - 1.f; }

#define RAWBAR() do{ \
  asm volatile("s_waitcnt lgkmcnt(0)" ::: "memory"); \
  __builtin_amdgcn_sched_barrier(0); \
  __builtin_amdgcn_s_barrier(); \
  __builtin_amdgcn_sched_barrier(0); \
}while(0)

// ---------------------------------------------------------------- fused prep
// blocks: [0,512) aemb (16 rows each) | [512,576) W | [576,704) U |
//         [704,961) mask + tagged h-image init
__global__ __launch_bounds__(320) void k_prep(const int* __restrict__ x,
                                              const float* __restrict__ emb,
                                              const float* __restrict__ Wf, const float* __restrict__ Wb,
                                              const float* __restrict__ bfv, const float* __restrict__ bbv,
                                              const float* __restrict__ Uf, const float* __restrict__ Ub,
                                              const float* __restrict__ h0f, const float* __restrict__ h0b,
                                              u16* __restrict__ aemb, u16* __restrict__ wpt,
                                              float* __restrict__ bias, u16* __restrict__ upt,
                                              u32* __restrict__ maskb, u32* __restrict__ himg){
  __shared__ u16 lbuf[320*64];                 // 40 KB, reused by wt/ut parts
  int bid = blockIdx.x, tid = threadIdx.x;

  if (bid < 512){                              // ---- aemb gather, 16 rows/block
    int k = tid;
    #pragma unroll 4
    for (int rr2 = 0; rr2 < 16; rr2++){
      int m = bid*16 + rr2;
      int b = m & 31, t = m >> 5;
      int tok = x[b*256 + t];
      float v = (k < 300) ? emb[(size_t)tok*300 + k] : 0.f;
      aemb[(size_t)m*EP + k] = f2bf(v);
    }
    return;
  }
  if (bid < 576){                              // ---- W -> [col'][K] + bias
    int b2 = bid - 512;                        // 0..63
    u16 (*lds)[64] = (u16(*)[64])lbuf;
    int c0 = b2*64; int dir = c0 >> 11;
    const float* W = dir ? Wb : Wf;
    if (tid < 256){
      int cl = tid & 63, rr = tid >> 6;
      int ci = (c0 + cl) & 2047; int srccol = (ci & 3)*512 + (ci >> 2);
      for (int kk = 0; kk < 80; kk++){
        int row = kk*4 + rr;
        float v = (row < 300) ? W[(size_t)row*2048 + srccol] : 0.f;
        lds[row][cl] = f2bf(v);
      }
    }
    __syncthreads();
    if (tid < 256){
      int cw = tid >> 2, kc = tid & 3;
      #pragma unroll
      for (int j = 0; j < 10; j++){
        u16x8 v;
        #pragma unroll
        for (int e = 0; e < 8; e++) v[e] = lds[kc*80 + j*8 + e][cw];
        *(u16x8*)&wpt[(size_t)(c0+cw)*EP + kc*80 + j*8] = v;
      }
      if (tid < 64){
        int ci2 = (c0 + tid) & 2047; int sc = (ci2 & 3)*512 + (ci2 >> 2);
        bias[c0 + tid] = (dir ? bbv : bfv)[sc];
      }
    }
    return;
  }
  if (bid < 704){                              // ---- U -> [col'][K]
    int b2 = bid - 576;                        // 0..127
    u16 (*lds)[32] = (u16(*)[32])lbuf;
    int cg0 = b2*32; int dir = cg0 >> 11;
    const float* U = dir ? Ub : Uf;
    if (tid < 256){
      int cl = tid & 31, rr = tid >> 5;
      int ci = (cg0 + cl) & 2047; int srccol = (ci & 3)*512 + (ci >> 2);
      for (int kk = 0; kk < 64; kk++){
        int row = kk*8 + rr;
        lds[row][cl] = f2bf(U[(size_t)row*2048 + srccol]);
      }
    }
    __syncthreads();
    if (tid < 256){
      int cw = tid >> 3, kc = tid & 7;
      #pragma unroll
      for (int j = 0; j < 8; j++){
        u16x8 v;
        #pragma unroll
        for (int e = 0; e < 8; e++) v[e] = lds[kc*64 + j*8 + e][cw];
        *(u16x8*)&upt[(size_t)(cg0+cw)*512 + kc*64 + j*8] = v;
      }
    }
    return;
  }
  {                                            // ---- mask + tagged image init
    int b2 = bid - 704;                        // 0..256
    if (tid >= 256) return;
    if (b2 == 256){
      int b = tid >> 3, w = tid & 7;
      u32 m = 0;
      for (int i = 0; i < 32; i++){ int t = w*32 + i; m |= (u32)(x[b*256 + t] != 0) << i; }
      maskb[b*8 + w] = m;
      return;
    }
    int idx = b2*256 + tid;                    // 0 .. 65535
    int dom = idx >> 14, rem = idx & 16383, par = rem >> 13, di = rem & 8191;
    int dir = dom >> 1, bh = dom & 1;
    u32* img = himg + (size_t)dom*16384 + (size_t)par*8192;
    if (par == 0){
      img[di] = 0x0000DEADu;                   // invalid tag
    } else {
      int j = di & 7, lane2 = (di >> 3) & 63, ks = di >> 9;
      int bl = lane2 & 15, q = lane2 >> 4;
      int ug = ks*32 + q*8 + j;
      int b = bh*16 + bl;
      const float* h0 = dir ? h0b : h0f;
      img[di] = ((u32)f2bf(h0[b*512 + ug]) << 16) | 0xFFFFu;   // h_{-1}, tag -1
    }
  }
}

// ---------------------------------------------------------------- persistent recurrence + fused xW
__global__ __launch_bounds__(512) void k_recur(const u16* __restrict__ aemb, const u16* __restrict__ wpt,
                                               const float* __restrict__ bias, const u16* __restrict__ upt,
                                               const u32* __restrict__ maskb, u32* __restrict__ himg,
                                               const float* __restrict__ c0f, const float* __restrict__ c0b,
                                               const float* __restrict__ h0f, const float* __restrict__ h0b,
                                               float* __restrict__ out){
  int bid = blockIdx.x;                        // 64 wgs
  int dir = bid & 1, bh = (bid >> 1) & 1, r = bid >> 2;   // domain (dir,bh), rank 0..15
  int tid = threadIdx.x, lane = tid & 63, wv = tid >> 6;
  int nt = wv;                                 // wave's N-tile (16 of the wg's 128 cols)

  __shared__ u16 astage[2][8192];              // double-buffered h frag image (32 KB)
  __shared__ u16 aembS[2][16*EPL];             // double-buffered x-emb rows (20.5 KB)
  __shared__ u32 mk[32][8];

  // U-slice (full K) + W-slice (K=320) as persistent B-fragments
  bf16x8 bfr[16], wfr[10];
  {
    const u16* ub = upt + ((size_t)dir*2048 + r*128 + nt*16 + (lane & 15))*512 + ((lane >> 4)*8);
    #pragma unroll
    for (int ks = 0; ks < 16; ks++)
      bfr[ks] = __builtin_bit_cast(bf16x8, *(const u16x8*)(ub + ks*32));
    const u16* wb = wpt + ((size_t)dir*2048 + r*128 + nt*16 + (lane & 15))*EP + ((lane >> 4)*8);
    #pragma unroll
    for (int ks = 0; ks < 10; ks++)
      wfr[ks] = __builtin_bit_cast(bf16x8, *(const u16x8*)(wb + ks*32));
  }

  // lane's post-transpose gate identity (R4/R12-validated mapping)
  int bq = (lane >> 4)*4 + (lane & 3);         // local batch row 0..15
  int u2 = (lane & 15) >> 2;
  int b  = bh*16 + bq;                         // global batch row
  int ug = r*32 + nt*4 + u2;
  float c_reg = (dir ? c0b : c0f)[b*512 + ug];
  float h_reg = (dir ? h0b : h0f)[b*512 + ug];
  f32x4 biasv = *(const f32x4*)&bias[dir*2048 + ug*4];
  if (tid < 256) mk[tid >> 3][tid & 7] = maskb[tid];

  u32* img = himg + (size_t)(dir*2 + bh)*16384;
  int qq = nt >> 1, j0 = (nt*4) & 7;
  size_t dpub = ((size_t)(r*64 + qq*16 + bq))*8 + j0;   // dword idx within parity buf
  bool sel0 = (lane & 1), sel1 = (lane & 2);
  int lb48 = lane & 48;

  // ---------------- prologue: stage aembS[0]<-t0, aembS[1]<-t1; xwv(t0); sg<-t2
  f32x4 xwv;
  u32x4 sg0, sg1;
  {
    int t0r = dir ? 255 : 0, t1r = dir ? 254 : 1;
    const char* s0 = (const char*)aemb + ((size_t)(t0r*32 + bh*16))*EP*2;
    const char* s1 = (const char*)aemb + ((size_t)(t1r*32 + bh*16))*EP*2;
    {
      u32x4 a0 = *(const u32x4*)(s0 + (size_t)tid*16);
      u32x4 a1 = *(const u32x4*)(s1 + (size_t)tid*16);
      int row = tid/40, k = tid - (tid/40)*40;
      *(u32x4*)((char*)&aembS[0][0] + row*(EPL*2) + k*16) = a0;
      *(u32x4*)((char*)&aembS[1][0] + row*(EPL*2) + k*16) = a1;
      if (tid < 128){
        int sl = 512 + tid;
        u32x4 b0 = *(const u32x4*)(s0 + (size_t)sl*16);
        u32x4 b1 = *(const u32x4*)(s1 + (size_t)sl*16);
        int row2 = sl/40, k2 = sl - (sl/40)*40;
        *(u32x4*)((char*)&aembS[0][0] + row2*(EPL*2) + k2*16) = b0;
        *(u32x4*)((char*)&aembS[1][0] + row2*(EPL*2) + k2*16) = b1;
      }
    }
    __syncthreads();
    f32x4 xacc = {0.f,0.f,0.f,0.f};
    const u16* al = &aembS[0][0] + (size_t)(lane & 15)*EPL + ((lane >> 4)*8);
    #pragma unroll
    for (int ks = 0; ks < 10; ks++){
      bf16x8 a = __builtin_bit_cast(bf16x8, *(const u16x8*)(al + ks*32));
      xacc = __builtin_amdgcn_mfma_f32_16x16x32_bf16(a, wfr[ks], xacc, 0, 0, 0);
    }
    f32x4 tt, rr, t2v, o;
    #pragma unroll
    for (int e = 0; e < 4; e++) tt[e] = __shfl_xor(xacc[e], 1);
    rr[0] = sel0 ? tt[1] : xacc[0];  rr[1] = sel0 ? xacc[1] : tt[0];
    rr[2] = sel0 ? tt[3] : xacc[2];  rr[3] = sel0 ? xacc[3] : tt[2];
    #pragma unroll
    for (int e = 0; e < 4; e++) t2v[e] = __shfl_xor(rr[e], 2);
    o[0] = sel1 ? t2v[2] : rr[0];  o[1] = sel1 ? t2v[3] : rr[1];
    o[2] = sel1 ? rr[2] : t2v[0];  o[3] = sel1 ? rr[3] : t2v[1];
    #pragma unroll
    for (int e = 0; e < 4; e++) xwv[e] = o[e] + biasv[e];

    int t2r = dir ? 253 : 2;
    const char* sa = (const char*)aemb + ((size_t)(t2r*32 + bh*16))*EP*2;
    sg0 = *(const u32x4*)(sa + (size_t)tid*16);
    if (tid < 128) sg1 = *(const u32x4*)(sa + (size_t)(512 + tid)*16);
  }

  // ---- polls live across iterations: issue for s=0 (parity 1, expect tag -1)
  u32x4 v0, v1, v2, v3;
  const char* gcur = (const char*)(img + 8192) + (size_t)tid*16;
  #define LD(i) asm volatile("global_load_dwordx4 %0, %1, off sc0 sc1" : "=v"(v##i) : "v"(gcur + i*8192))
  LD(0); LD(1); LD(2); LD(3);

  for (int s = 0; s < 256; ++s){
    int t = dir ? 255 - s : s;
    u32 tg = (u32)((s - 1) & 0xFFFF);
    int pr = (s + 1) & 1;

    // ---- verify tags == s-1 (polls already in flight), retry stale chunks
    {
      u32 pend = 15u;
      for (;;){
        asm volatile("s_waitcnt vmcnt(0)" ::: "memory");
        __builtin_amdgcn_sched_barrier(0);
        #define CK(i) if (pend & (1u << i)){ \
          if ((((v##i.x ^ tg) | (v##i.y ^ tg) | (v##i.z ^ tg) | (v##i.w ^ tg)) & 0xFFFFu) == 0u){ \
            u16 p0 = (u16)(v##i.x >> 16), p1 = (u16)(v##i.y >> 16), p2 = (u16)(v##i.z >> 16), p3 = (u16)(v##i.w >> 16); \
            u16* dst = (u16*)((char*)&astage[pr][0] + (size_t)tid*8 + i*4096); \
            dst[0] = p0; dst[1] = p1; dst[2] = p2; dst[3] = p3; \
            pend &= ~(1u << i); \
          } else { LD(i); } }
        CK(0); CK(1); CK(2); CK(3);
        #undef CK
        if (!pend) break;
      }
    }
    RAWBAR();                                   // astage[pr] ready (single barrier/step)

    // ---- ds_write staged aemb rows (t_{s+2}) into aembS[s&1]
    if (s < 254){
      int row0 = tid/40, k0 = tid - (tid/40)*40;
      *(u32x4*)((char*)&aembS[s & 1][0] + row0*(EPL*2) + k0*16) = sg0;
      if (tid < 128){
        int sl = 512 + tid;
        int row1 = sl/40, k1 = sl - (sl/40)*40;
        *(u32x4*)((char*)&aembS[s & 1][0] + row1*(EPL*2) + k1*16) = sg1;
      }
    }

    // ---- z = h_{s-1} @ U : 16 MFMA, full K
    f32x4 acc = {0.f, 0.f, 0.f, 0.f};
    {
      const u16* ab = &astage[pr][0] + lane*8;
      #pragma unroll
      for (int ks = 0; ks < 16; ks++){
        bf16x8 a = __builtin_bit_cast(bf16x8, *(const u16x8*)(ab + (size_t)ks*512));
        acc = __builtin_amdgcn_mfma_f32_16x16x32_bf16(a, bfr[ks], acc, 0, 0, 0);
      }
    }

    // ---- in-wave quad 4x4 transpose
    f32x4 tt, rr, t2v, o;
    #pragma unroll
    for (int e = 0; e < 4; e++) tt[e] = __shfl_xor(acc[e], 1);
    rr[0] = sel0 ? tt[1] : acc[0];  rr[1] = sel0 ? acc[1] : tt[0];
    rr[2] = sel0 ? tt[3] : acc[2];  rr[3] = sel0 ? acc[3] : tt[2];
    #pragma unroll
    for (int e = 0; e < 4; e++) t2v[e] = __shfl_xor(rr[e], 2);
    o[0] = sel1 ? t2v[2] : rr[0];  o[1] = sel1 ? t2v[3] : rr[1];
    o[2] = sel1 ? rr[2] : t2v[0];  o[3] = sel1 ? rr[3] : t2v[1];

    // ---- gates (lane owns batch b, unit ug); xwv = xW+b fp32 from last iter
    float zi = o[0] + xwv[0];
    float zf = o[1] + xwv[1];
    float zg = o[2] + xwv[2];
    float zo = o[3] + xwv[3];
    float gi = sigm(zi), gf = sigm(zf), gg = tanh_(zg), go = sigm(zo);
    float cn = gf*c_reg + gi*gg;
    float hn = go*tanh_(cn);
    if ((mk[b][t >> 5] >> (t & 31)) & 1){ c_reg = cn; h_reg = hn; }

    // ---- publish: quad-packed tagged dwordx4 (one store per 4 lanes)
    {
      float hA = __shfl(h_reg, lb48 | ((lane + 4)  & 15));
      float hB = __shfl(h_reg, lb48 | ((lane + 8)  & 15));
      float hC = __shfl(h_reg, lb48 | ((lane + 12) & 15));
      if (u2 == 0 && s < 255){
        u32 tgp = (u32)s;
        u32x4 dw;
        dw.x = ((u32)f2bf(h_reg) << 16) | tgp;
        dw.y = ((u32)f2bf(hA)    << 16) | tgp;
        dw.z = ((u32)f2bf(hB)    << 16) | tgp;
        dw.w = ((u32)f2bf(hC)    << 16) | tgp;
        u32* gdst = img + (size_t)(s & 1)*8192 + dpub;
        asm volatile("global_store_dwordx4 %0, %1, off sc0 sc1" :: "v"(gdst), "v"(dw) : "memory");
      }
    }

    // ---- issue polls for s+1 NOW (parity s&1, expect tag s) — age under xwv
    if (s < 255){
      gcur = (const char*)(img + (size_t)(s & 1)*8192) + (size_t)tid*16;
      LD(0); LD(1); LD(2); LD(3);
    }

    // ---- post-publish window: out-store h_s, sg <- t_{s+3}, compute xwv
    out[(size_t)(b*256 + t)*1024 + dir*512 + ug] = h_reg;
    if (s < 253){
      int t3r = dir ? 252 - s : s + 3;
      const char* sa = (const char*)aemb + ((size_t)(t3r*32 + bh*16))*EP*2;
      sg0 = *(const u32x4*)(sa + (size_t)tid*16);
      if (tid < 128) sg1 = *(const u32x4*)(sa + (size_t)(512 + tid)*16);
    }
    if (s < 255){
      f32x4 xacc = {0.f,0.f,0.f,0.f};
      const u16* al = &aembS[(s + 1) & 1][0] + (size_t)(lane & 15)*EPL + ((lane >> 4)*8);
      #pragma unroll
      for (int ks = 0; ks < 10; ks++){
        bf16x8 a = __builtin_bit_cast(bf16x8, *(const u16x8*)(al + ks*32));
        xacc = __builtin_amdgcn_mfma_f32_16x16x32_bf16(a, wfr[ks], xacc, 0, 0, 0);
      }
      f32x4 xt, xr, x2, xo;
      #pragma unroll
      for (int e = 0; e < 4; e++) xt[e] = __shfl_xor(xacc[e], 1);
      xr[0] = sel0 ? xt[1] : xacc[0];  xr[1] = sel0 ? xacc[1] : xt[0];
      xr[2] = sel0 ? xt[3] : xacc[2];  xr[3] = sel0 ? xacc[3] : xt[2];
      #pragma unroll
      for (int e = 0; e < 4; e++) x2[e] = __shfl_xor(xr[e], 2);
      xo[0] = sel1 ? x2[2] : xr[0];  xo[1] = sel1 ? x2[3] : xr[1];
      xo[2] = sel1 ? xr[2] : x2[0];  xo[3] = sel1 ? xr[3] : x2[1];
      #pragma unroll
      for (int e = 0; e < 4; e++) xwv[e] = xo[e] + biasv[e];
    }
  }
  #undef LD

  // ---- finals
  out[8388608 + dir*16384 + b*512 + ug] = h_reg;                // h_f / h_b
  out[8388608 + 32768 + dir*16384 + b*512 + ug] = c_reg;        // c_f / c_b
}

// ----------------------------------------------------------------------------
extern "C" void kernel_launch(void* const* d_in, const int* in_sizes, int n_in,
                              void* d_out, int out_size, void* d_ws, size_t ws_size,
                              hipStream_t stream){
  const int*   x   = (const int*)  d_in[0];
  const float* h0f = (const float*)d_in[1];
  const float* c0f = (const float*)d_in[2];
  const float* h0b = (const float*)d_in[3];
  const float* c0b = (const float*)d_in[4];
  const float* emb = (const float*)d_in[5];
  const float* Wf  = (const float*)d_in[6];
  const float* Uf  = (const float*)d_in[7];
  const float* bfv = (const float*)d_in[8];
  const float* Wb  = (const float*)d_in[9];
  const float* Ub  = (const float*)d_in[10];
  const float* bbv = (const float*)d_in[11];
  float* out = (float*)d_out;

  char* w = (char*)d_ws;
  u16*   aemb = (u16*)(w + OFF_AEMB);
  u16*   wpt  = (u16*)(w + OFF_WPT);
  float* bias = (float*)(w + OFF_BIAS);
  u16*   upt  = (u16*)(w + OFF_UPT);
  u32*   mskb = (u32*)(w + OFF_MASK);
  u32*   himg = (u32*)(w + OFF_HIMG);

  k_prep <<<dim3(961), dim3(320), 0, stream>>>(x, emb, Wf, Wb, bfv, bbv, Uf, Ub,
                                               h0f, h0b, aemb, wpt, bias, upt, mskb, himg);
  k_recur<<<dim3(64),  dim3(512), 0, stream>>>(aemb, wpt, bias, upt, mskb, himg,
                                               c0f, c0b, h0f, h0b, out);
}

// Round 16
// 609.397 us; speedup vs baseline: 1.3737x; 1.3737x over previous
//
#include <hip/hip_runtime.h>

// ============================================================================
// Bidirectional LSTM encoder, MI355X.  R16: R14 k_recur (best) + R15 fat prep.
//   - 4 domains (dir x batch-half) x 16 wgs; 8 waves x (16x16 tile, full-K).
//   - polls issued at TOP of iteration (sample late = round-1 hit); verify
//     window contains only the 4 tagged poll loads.
//   - tag-in-data sync, quad-packed publish, 1 RAWBAR/step, in-wave quad
//     transpose gates, xW fold, staging distance 3.
// ============================================================================

typedef unsigned short u16;
typedef unsigned int   u32;
typedef u16   u16x8 __attribute__((ext_vector_type(8)));
typedef u32   u32x4 __attribute__((ext_vector_type(4)));
typedef __bf16 bf16x8 __attribute__((ext_vector_type(8)));
typedef float f32x4 __attribute__((ext_vector_type(4)));

#define EP 320            // padded E (300 -> 320)
#define EPL 328           // LDS row stride (pad -> 2-way banks only)

static const size_t OFF_AEMB = 0;                              // 8192*320*2
static const size_t OFF_WPT  = OFF_AEMB + (size_t)8192*EP*2;
static const size_t OFF_BIAS = OFF_WPT  + (size_t)4096*EP*2;   // f32[4096]
static const size_t OFF_UPT  = OFF_BIAS + (size_t)4096*4;      // bf16 [4096][512]
static const size_t OFF_MASK = OFF_UPT  + (size_t)4096*512*2;  // u32 [32][8]
static const size_t OFF_HIMG = OFF_MASK + 1024;                // u32 4dom*2par*8192 dwords

__device__ __forceinline__ u16 f2bf(float f){               // RNE
  u32 u = __builtin_bit_cast(u32, f);
  return (u16)((u + 0x7FFFu + ((u >> 16) & 1u)) >> 16);
}
__device__ __forceinline__ float sigm(float x){ return 1.f/(1.f+__expf(-x)); }
__device__ __forceinline__ float tanh_(float x){ return 2.f/(1.f+__expf(-2.f*x)) - 1.f; }

#define RAWBAR() do{ \
  asm volatile("s_waitcnt lgkmcnt(0)" ::: "memory"); \
  __builtin_amdgcn_sched_barrier(0); \
  __builtin_amdgcn_s_barrier(); \
  __builtin_amdgcn_sched_barrier(0); \
}while(0)

// ---------------------------------------------------------------- fused prep
// blocks: [0,512) aemb (16 rows each) | [512,576) W | [576,704) U |
//         [704,961) mask + tagged h-image init
__global__ __launch_bounds__(320) void k_prep(const int* __restrict__ x,
                                              const float* __restrict__ emb,
                                              const float* __restrict__ Wf, const float* __restrict__ Wb,
                                              const float* __restrict__ bfv, const float* __restrict__ bbv,
                                              const float* __restrict__ Uf, const float* __restrict__ Ub,
                                              const float* __restrict__ h0f, const float* __restrict__ h0b,
                                              u16* __restrict__ aemb, u16* __restrict__ wpt,
                                              float* __restrict__ bias, u16* __restrict__ upt,
                                              u32* __restrict__ maskb, u32* __restrict__ himg){
  __shared__ u16 lbuf[320*64];                 // 40 KB, reused by wt/ut parts
  int bid = blockIdx.x, tid = threadIdx.x;

  if (bid < 512){                              // ---- aemb gather, 16 rows/block
    int k = tid;
    #pragma unroll 4
    for (int rr2 = 0; rr2 < 16; rr2++){
      int m = bid*16 + rr2;
      int b = m & 31, t = m >> 5;
      int tok = x[b*256 + t];
      float v = (k < 300) ? emb[(size_t)tok*300 + k] : 0.f;
      aemb[(size_t)m*EP + k] = f2bf(v);
    }
    return;
  }
  if (bid < 576){                              // ---- W -> [col'][K] + bias
    int b2 = bid - 512;                        // 0..63
    u16 (*lds)[64] = (u16(*)[64])lbuf;
    int c0 = b2*64; int dir = c0 >> 11;
    const float* W = dir ? Wb : Wf;
    if (tid < 256){
      int cl = tid & 63, rr = tid >> 6;
      int ci = (c0 + cl) & 2047; int srccol = (ci & 3)*512 + (ci >> 2);
      for (int kk = 0; kk < 80; kk++){
        int row = kk*4 + rr;
        float v = (row < 300) ? W[(size_t)row*2048 + srccol] : 0.f;
        lds[row][cl] = f2bf(v);
      }
    }
    __syncthreads();
    if (tid < 256){
      int cw = tid >> 2, kc = tid & 3;
      #pragma unroll
      for (int j = 0; j < 10; j++){
        u16x8 v;
        #pragma unroll
        for (int e = 0; e < 8; e++) v[e] = lds[kc*80 + j*8 + e][cw];
        *(u16x8*)&wpt[(size_t)(c0+cw)*EP + kc*80 + j*8] = v;
      }
      if (tid < 64){
        int ci2 = (c0 + tid) & 2047; int sc = (ci2 & 3)*512 + (ci2 >> 2);
        bias[c0 + tid] = (dir ? bbv : bfv)[sc];
      }
    }
    return;
  }
  if (bid < 704){                              // ---- U -> [col'][K]
    int b2 = bid - 576;                        // 0..127
    u16 (*lds)[32] = (u16(*)[32])lbuf;
    int cg0 = b2*32; int dir = cg0 >> 11;
    const float* U = dir ? Ub : Uf;
    if (tid < 256){
      int cl = tid & 31, rr = tid >> 5;
      int ci = (cg0 + cl) & 2047; int srccol = (ci & 3)*512 + (ci >> 2);
      for (int kk = 0; kk < 64; kk++){
        int row = kk*8 + rr;
        lds[row][cl] = f2bf(U[(size_t)row*2048 + srccol]);
      }
    }
    __syncthreads();
    if (tid < 256){
      int cw = tid >> 3, kc = tid & 7;
      #pragma unroll
      for (int j = 0; j < 8; j++){
        u16x8 v;
        #pragma unroll
        for (int e = 0; e < 8; e++) v[e] = lds[kc*64 + j*8 + e][cw];
        *(u16x8*)&upt[(size_t)(cg0+cw)*512 + kc*64 + j*8] = v;
      }
    }
    return;
  }
  {                                            // ---- mask + tagged image init
    int b2 = bid - 704;                        // 0..256
    if (tid >= 256) return;
    if (b2 == 256){
      int b = tid >> 3, w = tid & 7;
      u32 m = 0;
      for (int i = 0; i < 32; i++){ int t = w*32 + i; m |= (u32)(x[b*256 + t] != 0) << i; }
      maskb[b*8 + w] = m;
      return;
    }
    int idx = b2*256 + tid;                    // 0 .. 65535
    int dom = idx >> 14, rem = idx & 16383, par = rem >> 13, di = rem & 8191;
    int dir = dom >> 1, bh = dom & 1;
    u32* img = himg + (size_t)dom*16384 + (size_t)par*8192;
    if (par == 0){
      img[di] = 0x0000DEADu;                   // invalid tag
    } else {
      int j = di & 7, lane2 = (di >> 3) & 63, ks = di >> 9;
      int bl = lane2 & 15, q = lane2 >> 4;
      int ug = ks*32 + q*8 + j;
      int b = bh*16 + bl;
      const float* h0 = dir ? h0b : h0f;
      img[di] = ((u32)f2bf(h0[b*512 + ug]) << 16) | 0xFFFFu;   // h_{-1}, tag -1
    }
  }
}

// ---------------------------------------------------------------- persistent recurrence + fused xW
__global__ __launch_bounds__(512) void k_recur(const u16* __restrict__ aemb, const u16* __restrict__ wpt,
                                               const float* __restrict__ bias, const u16* __restrict__ upt,
                                               const u32* __restrict__ maskb, u32* __restrict__ himg,
                                               const float* __restrict__ c0f, const float* __restrict__ c0b,
                                               const float* __restrict__ h0f, const float* __restrict__ h0b,
                                               float* __restrict__ out){
  int bid = blockIdx.x;                        // 64 wgs
  int dir = bid & 1, bh = (bid >> 1) & 1, r = bid >> 2;   // domain (dir,bh), rank 0..15
  int tid = threadIdx.x, lane = tid & 63, wv = tid >> 6;
  int nt = wv;                                 // wave's N-tile (16 of the wg's 128 cols)

  __shared__ u16 astage[2][8192];              // double-buffered h frag image (32 KB)
  __shared__ u16 aembS[2][16*EPL];             // double-buffered x-emb rows (20.5 KB)
  __shared__ u32 mk[32][8];

  // U-slice (full K) + W-slice (K=320) as persistent B-fragments
  bf16x8 bfr[16], wfr[10];
  {
    const u16* ub = upt + ((size_t)dir*2048 + r*128 + nt*16 + (lane & 15))*512 + ((lane >> 4)*8);
    #pragma unroll
    for (int ks = 0; ks < 16; ks++)
      bfr[ks] = __builtin_bit_cast(bf16x8, *(const u16x8*)(ub + ks*32));
    const u16* wb = wpt + ((size_t)dir*2048 + r*128 + nt*16 + (lane & 15))*EP + ((lane >> 4)*8);
    #pragma unroll
    for (int ks = 0; ks < 10; ks++)
      wfr[ks] = __builtin_bit_cast(bf16x8, *(const u16x8*)(wb + ks*32));
  }

  // lane's post-transpose gate identity (R4/R12-validated mapping)
  int bq = (lane >> 4)*4 + (lane & 3);         // local batch row 0..15
  int u2 = (lane & 15) >> 2;
  int b  = bh*16 + bq;                         // global batch row
  int ug = r*32 + nt*4 + u2;
  float c_reg = (dir ? c0b : c0f)[b*512 + ug];
  float h_reg = (dir ? h0b : h0f)[b*512 + ug];
  f32x4 biasv = *(const f32x4*)&bias[dir*2048 + ug*4];
  if (tid < 256) mk[tid >> 3][tid & 7] = maskb[tid];

  u32* img = himg + (size_t)(dir*2 + bh)*16384;
  int qq = nt >> 1, j0 = (nt*4) & 7;
  size_t dpub = ((size_t)(r*64 + qq*16 + bq))*8 + j0;   // dword idx within parity buf
  bool sel0 = (lane & 1), sel1 = (lane & 2);
  int lb48 = lane & 48;

  // ---------------- prologue: stage aembS[0]<-t0, aembS[1]<-t1; xwv(t0); sg<-t2
  f32x4 xwv;
  u32x4 sg0, sg1;
  {
    int t0r = dir ? 255 : 0, t1r = dir ? 254 : 1;
    const char* s0 = (const char*)aemb + ((size_t)(t0r*32 + bh*16))*EP*2;
    const char* s1 = (const char*)aemb + ((size_t)(t1r*32 + bh*16))*EP*2;
    {
      u32x4 a0 = *(const u32x4*)(s0 + (size_t)tid*16);
      u32x4 a1 = *(const u32x4*)(s1 + (size_t)tid*16);
      int row = tid/40, k = tid - (tid/40)*40;
      *(u32x4*)((char*)&aembS[0][0] + row*(EPL*2) + k*16) = a0;
      *(u32x4*)((char*)&aembS[1][0] + row*(EPL*2) + k*16) = a1;
      if (tid < 128){
        int sl = 512 + tid;
        u32x4 b0 = *(const u32x4*)(s0 + (size_t)sl*16);
        u32x4 b1 = *(const u32x4*)(s1 + (size_t)sl*16);
        int row2 = sl/40, k2 = sl - (sl/40)*40;
        *(u32x4*)((char*)&aembS[0][0] + row2*(EPL*2) + k2*16) = b0;
        *(u32x4*)((char*)&aembS[1][0] + row2*(EPL*2) + k2*16) = b1;
      }
    }
    __syncthreads();
    f32x4 xacc = {0.f,0.f,0.f,0.f};
    const u16* al = &aembS[0][0] + (size_t)(lane & 15)*EPL + ((lane >> 4)*8);
    #pragma unroll
    for (int ks = 0; ks < 10; ks++){
      bf16x8 a = __builtin_bit_cast(bf16x8, *(const u16x8*)(al + ks*32));
      xacc = __builtin_amdgcn_mfma_f32_16x16x32_bf16(a, wfr[ks], xacc, 0, 0, 0);
    }
    f32x4 tt, rr, t2v, o;
    #pragma unroll
    for (int e = 0; e < 4; e++) tt[e] = __shfl_xor(xacc[e], 1);
    rr[0] = sel0 ? tt[1] : xacc[0];  rr[1] = sel0 ? xacc[1] : tt[0];
    rr[2] = sel0 ? tt[3] : xacc[2];  rr[3] = sel0 ? xacc[3] : tt[2];
    #pragma unroll
    for (int e = 0; e < 4; e++) t2v[e] = __shfl_xor(rr[e], 2);
    o[0] = sel1 ? t2v[2] : rr[0];  o[1] = sel1 ? t2v[3] : rr[1];
    o[2] = sel1 ? rr[2] : t2v[0];  o[3] = sel1 ? rr[3] : t2v[1];
    #pragma unroll
    for (int e = 0; e < 4; e++) xwv[e] = o[e] + biasv[e];

    // issue sg <- t2 (consumed by ds_write at s=0)
    int t2r = dir ? 253 : 2;
    const char* sa = (const char*)aemb + ((size_t)(t2r*32 + bh*16))*EP*2;
    sg0 = *(const u32x4*)(sa + (size_t)tid*16);
    if (tid < 128) sg1 = *(const u32x4*)(sa + (size_t)(512 + tid)*16);
  }

  for (int s = 0; s < 256; ++s){
    int t = dir ? 255 - s : s;
    u32 tg = (u32)((s - 1) & 0xFFFF);
    int pr = (s + 1) & 1;

    // ---- issue 4 tagged chunk loads; verify window = polls only
    const char* gsrc = (const char*)(img + (size_t)pr*8192) + (size_t)tid*16;
    u32x4 v0, v1, v2, v3;
    #define LD(i) asm volatile("global_load_dwordx4 %0, %1, off sc0 sc1" : "=v"(v##i) : "v"(gsrc + i*8192))
    LD(0); LD(1); LD(2); LD(3);
    {
      u32 pend = 15u;
      for (;;){
        asm volatile("s_waitcnt vmcnt(0)" ::: "memory");
        __builtin_amdgcn_sched_barrier(0);
        #define CK(i) if (pend & (1u << i)){ \
          if ((((v##i.x ^ tg) | (v##i.y ^ tg) | (v##i.z ^ tg) | (v##i.w ^ tg)) & 0xFFFFu) == 0u){ \
            u16 p0 = (u16)(v##i.x >> 16), p1 = (u16)(v##i.y >> 16), p2 = (u16)(v##i.z >> 16), p3 = (u16)(v##i.w >> 16); \
            u16* dst = (u16*)((char*)&astage[pr][0] + (size_t)tid*8 + i*4096); \
            dst[0] = p0; dst[1] = p1; dst[2] = p2; dst[3] = p3; \
            pend &= ~(1u << i); \
          } else { LD(i); } }
        CK(0); CK(1); CK(2); CK(3);
        #undef CK
        if (!pend) break;
      }
    }
    #undef LD
    RAWBAR();                                   // astage[pr] ready (single barrier/step)

    // ---- ds_write staged aemb rows (t_{s+2}) into aembS[s&1]
    if (s < 254){
      int row0 = tid/40, k0 = tid - (tid/40)*40;
      *(u32x4*)((char*)&aembS[s & 1][0] + row0*(EPL*2) + k0*16) = sg0;
      if (tid < 128){
        int sl = 512 + tid;
        int row1 = sl/40, k1 = sl - (sl/40)*40;
        *(u32x4*)((char*)&aembS[s & 1][0] + row1*(EPL*2) + k1*16) = sg1;
      }
    }

    // ---- z = h_{s-1} @ U : 16 MFMA, full K
    f32x4 acc = {0.f, 0.f, 0.f, 0.f};
    {
      const u16* ab = &astage[pr][0] + lane*8;
      #pragma unroll
      for (int ks = 0; ks < 16; ks++){
        bf16x8 a = __builtin_bit_cast(bf16x8, *(const u16x8*)(ab + (size_t)ks*512));
        acc = __builtin_amdgcn_mfma_f32_16x16x32_bf16(a, bfr[ks], acc, 0, 0, 0);
      }
    }

    // ---- in-wave quad 4x4 transpose
    f32x4 tt, rr, t2v, o;
    #pragma unroll
    for (int e = 0; e < 4; e++) tt[e] = __shfl_xor(acc[e], 1);
    rr[0] = sel0 ? tt[1] : acc[0];  rr[1] = sel0 ? acc[1] : tt[0];
    rr[2] = sel0 ? tt[3] : acc[2];  rr[3] = sel0 ? acc[3] : tt[2];
    #pragma unroll
    for (int e = 0; e < 4; e++) t2v[e] = __shfl_xor(rr[e], 2);
    o[0] = sel1 ? t2v[2] : rr[0];  o[1] = sel1 ? t2v[3] : rr[1];
    o[2] = sel1 ? rr[2] : t2v[0];  o[3] = sel1 ? rr[3] : t2v[1];

    // ---- gates (lane owns batch b, unit ug); xwv = xW+b fp32 from last iter
    float zi = o[0] + xwv[0];
    float zf = o[1] + xwv[1];
    float zg = o[2] + xwv[2];
    float zo = o[3] + xwv[3];
    float gi = sigm(zi), gf = sigm(zf), gg = tanh_(zg), go = sigm(zo);
    float cn = gf*c_reg + gi*gg;
    float hn = go*tanh_(cn);
    if ((mk[b][t >> 5] >> (t & 31)) & 1){ c_reg = cn; h_reg = hn; }

    // ---- publish: quad-packed tagged dwordx4 (one store per 4 lanes)
    {
      float hA = __shfl(h_reg, lb48 | ((lane + 4)  & 15));
      float hB = __shfl(h_reg, lb48 | ((lane + 8)  & 15));
      float hC = __shfl(h_reg, lb48 | ((lane + 12) & 15));
      if (u2 == 0 && s < 255){
        u32 tgp = (u32)s;
        u32x4 dw;
        dw.x = ((u32)f2bf(h_reg) << 16) | tgp;
        dw.y = ((u32)f2bf(hA)    << 16) | tgp;
        dw.z = ((u32)f2bf(hB)    << 16) | tgp;
        dw.w = ((u32)f2bf(hC)    << 16) | tgp;
        u32* gdst = img + (size_t)(s & 1)*8192 + dpub;
        asm volatile("global_store_dwordx4 %0, %1, off sc0 sc1" :: "v"(gdst), "v"(dw) : "memory");
      }
    }

    // ---- post-publish window: out-store h_s, issue sg <- t_{s+3}, compute xwv
    out[(size_t)(b*256 + t)*1024 + dir*512 + ug] = h_reg;
    if (s < 253){
      int t3r = dir ? 252 - s : s + 3;
      const char* sa = (const char*)aemb + ((size_t)(t3r*32 + bh*16))*EP*2;
      sg0 = *(const u32x4*)(sa + (size_t)tid*16);
      if (tid < 128) sg1 = *(const u32x4*)(sa + (size_t)(512 + tid)*16);
    }
    if (s < 255){
      f32x4 xacc = {0.f,0.f,0.f,0.f};
      const u16* al = &aembS[(s + 1) & 1][0] + (size_t)(lane & 15)*EPL + ((lane >> 4)*8);
      #pragma unroll
      for (int ks = 0; ks < 10; ks++){
        bf16x8 a = __builtin_bit_cast(bf16x8, *(const u16x8*)(al + ks*32));
        xacc = __builtin_amdgcn_mfma_f32_16x16x32_bf16(a, wfr[ks], xacc, 0, 0, 0);
      }
      f32x4 xt, xr, x2, xo;
      #pragma unroll
      for (int e = 0; e < 4; e++) xt[e] = __shfl_xor(xacc[e], 1);
      xr[0] = sel0 ? xt[1] : xacc[0];  xr[1] = sel0 ? xacc[1] : xt[0];
      xr[2] = sel0 ? xt[3] : xacc[2];  xr[3] = sel0 ? xacc[3] : xt[2];
      #pragma unroll
      for (int e = 0; e < 4; e++) x2[e] = __shfl_xor(xr[e], 2);
      xo[0] = sel1 ? x2[2] : xr[0];  xo[1] = sel1 ? x2[3] : xr[1];
      xo[2] = sel1 ? xr[2] : x2[0];  xo[3] = sel1 ? xr[3] : x2[1];
      #pragma unroll
      for (int e = 0; e < 4; e++) xwv[e] = xo[e] + biasv[e];
    }
  }

  // ---- finals
  out[8388608 + dir*16384 + b*512 + ug] = h_reg;                // h_f / h_b
  out[8388608 + 32768 + dir*16384 + b*512 + ug] = c_reg;        // c_f / c_b
}

// ----------------------------------------------------------------------------
extern "C" void kernel_launch(void* const* d_in, const int* in_sizes, int n_in,
                              void* d_out, int out_size, void* d_ws, size_t ws_size,
                              hipStream_t stream){
  const int*   x   = (const int*)  d_in[0];
  const float* h0f = (const float*)d_in[1];
  const float* c0f = (const float*)d_in[2];
  const float* h0b = (const float*)d_in[3];
  const float* c0b = (const float*)d_in[4];
  const float* emb = (const float*)d_in[5];
  const float* Wf  = (const float*)d_in[6];
  const float* Uf  = (const float*)d_in[7];
  const float* bfv = (const float*)d_in[8];
  const float* Wb  = (const float*)d_in[9];
  const float* Ub  = (const float*)d_in[10];
  const float* bbv = (const float*)d_in[11];
  float* out = (float*)d_out;

  char* w = (char*)d_ws;
  u16*   aemb = (u16*)(w + OFF_AEMB);
  u16*   wpt  = (u16*)(w + OFF_WPT);
  float* bias = (float*)(w + OFF_BIAS);
  u16*   upt  = (u16*)(w + OFF_UPT);
  u32*   mskb = (u32*)(w + OFF_MASK);
  u32*   himg = (u32*)(w + OFF_HIMG);

  k_prep <<<dim3(961), dim3(320), 0, stream>>>(x, emb, Wf, Wb, bfv, bbv, Uf, Ub,
                                               h0f, h0b, aemb, wpt, bias, upt, mskb, himg);
  k_recur<<<dim3(64),  dim3(512), 0, stream>>>(aemb, wpt, bias, upt, mskb, himg,
                                               c0f, c0b, h0f, h0b, out);
}